// Round 2
// baseline (920.299 us; speedup 1.0000x reference)
//
#include <hip/hip_runtime.h>

typedef unsigned short u16;
typedef __bf16 bf16x8 __attribute__((ext_vector_type(8)));
typedef float f32x4 __attribute__((ext_vector_type(4)));

#define B_   256
#define C_   2048
#define P_   196
#define A_   512
#define CP_  (C_ * P_)        // 401408
#define MTOT (B_ * P_)        // 50176 = 784 * 64

#define BM 64                 // rows per block
#define BK 32                 // k per iter (one 16x16x32 kstep)
#define NBLK (MTOT / BM)      // 784

__device__ __forceinline__ u16 f2bf(float f) {
    unsigned int x = __float_as_uint(f);
    unsigned int r = (x + 0x7fffu + ((x >> 16) & 1u)) >> 16;   // RNE
    return (u16)r;
}

__device__ __forceinline__ unsigned long long pack4bf(const float* v) {
    unsigned int lo = (unsigned int)f2bf(v[0]) | ((unsigned int)f2bf(v[1]) << 16);
    unsigned int hi = (unsigned int)f2bf(v[2]) | ((unsigned int)f2bf(v[3]) << 16);
    return (unsigned long long)lo | ((unsigned long long)hi << 32);
}

// async global->LDS 16B copy; LDS dest is wave-uniform base + lane*16
__device__ __forceinline__ void gl_lds16(const void* g, void* l) {
    __builtin_amdgcn_global_load_lds(
        (const __attribute__((address_space(1))) unsigned int*)g,
        (__attribute__((address_space(3))) unsigned int*)l, 16, 0, 0);
}

// Compiler-level fence: pins program (and thus vmcnt-FIFO) order of memory ops.
#define FENCE() asm volatile("" ::: "memory")
// Counted barrier: wait vmem down to N outstanding (leaves the N newest loads
// in flight across the barrier), drain LDS ops, then barrier.  Single asm so
// nothing is scheduled between the wait and the barrier.
#define BAR_VM(N) asm volatile("s_waitcnt vmcnt(" #N ") lgkmcnt(0)\n\ts_barrier" ::: "memory")

// ---------------------------------------------------------------------------
// Kernel 1: Wt[a][c] = bf16(W_enc[c][a])   (2048x512 -> 512x2048)
// ---------------------------------------------------------------------------
__global__ __launch_bounds__(256) void k_transpose_wenc(const float* __restrict__ W,
                                                        u16* __restrict__ Wt) {
    __shared__ u16 tile[64][65];
    int t  = threadIdx.x;
    int cb = (blockIdx.x & 31) * 64;
    int ab = (blockIdx.x >> 5) * 64;
#pragma unroll
    for (int i = 0; i < 16; ++i) {
        int c = (t >> 6) + i * 4;
        int a = t & 63;
        tile[c][a] = f2bf(W[(size_t)(cb + c) * A_ + ab + a]);
    }
    __syncthreads();
#pragma unroll
    for (int i = 0; i < 16; ++i) {
        int a  = (t >> 6) + i * 4;
        int cl = t & 63;
        Wt[(size_t)(ab + a) * C_ + cb + cl] = tile[cl][a];
    }
}

// ---------------------------------------------------------------------------
// Kernel 2: dec_att[b][a] = dh[b] @ W_dec[:,a] + b_dec[a]
// ---------------------------------------------------------------------------
__global__ __launch_bounds__(512) void k_dec_att(const float* __restrict__ dh,
                                                 const float* __restrict__ Wd,
                                                 const float* __restrict__ bd,
                                                 float* __restrict__ out) {
    __shared__ float hL[512];
    int b = blockIdx.x, t = threadIdx.x;
    hL[t] = dh[b * 512 + t];
    __syncthreads();
    float s = bd[t];
#pragma unroll 8
    for (int k = 0; k < 512; ++k) s = fmaf(hL[k], Wd[k * 512 + t], s);
    out[b * 512 + t] = s;
}

// ---------------------------------------------------------------------------
// Kernel 3: fused att GEMM.  64 rows x 512 a per block, 512 thr = 8 waves,
// wave = 64r x 64a (acc 4x4 of 16x16), K=2048, BK=32.
//   A (feats): fp32 gather -> reg -> bf16 pack -> ds_write (frag order),
//              double-buffered As; gathers prefetched ~2 iters ahead and
//              carried ACROSS barriers (counted vmcnt).
//   B (Wt):    global_load_lds dwordx4 into Bs, double-buffered, issued at
//              iter top, drained by the counted barrier at iter end.
//   Barrier  = s_waitcnt vmcnt(4) lgkmcnt(0); s_barrier  -- leaves the 4
//              newest A-gather loads in flight (FIFO: draining to depth 4
//              retires exactly B-DMA + previous A set).
//   LDS 78 KB -> 2 blocks/CU: cross-block overlap covers residual stalls.
// ---------------------------------------------------------------------------
#define GEMM_BODY(KK, P, AV, DO_B, DO_PACK, DO_A, VMN)                               \
  {                                                                                  \
    if (DO_B) {                                                                      \
      const u16* sB = srcB + (size_t)((KK) + 1) * 32;                                \
      gl_lds16(sB,                   &Bs[(P) ^ 1][b_off]);                           \
      gl_lds16(sB + (size_t)16 * C_, &Bs[(P) ^ 1][b_off + 512]);                     \
      gl_lds16(sB + (size_t)32 * C_, &Bs[(P) ^ 1][b_off + 1024]);                    \
      gl_lds16(sB + (size_t)48 * C_, &Bs[(P) ^ 1][b_off + 1536]);                    \
      FENCE();                                                                       \
    }                                                                                \
    bf16x8 bfr[4];                                                                   \
    _Pragma("unroll")                                                                \
    for (int tr = 0; tr < 4; ++tr)                                                   \
      bfr[tr] = *(const bf16x8*)&As[P][tr * 512 + lane * 8];                         \
    _Pragma("unroll")                                                                \
    for (int ta = 0; ta < 4; ++ta) {                                                 \
      bf16x8 afr = *(const bf16x8*)&Bs[P][(wv * 4 + ta) * 512 + lane * 8];           \
      _Pragma("unroll")                                                              \
      for (int tr = 0; tr < 4; ++tr)                                                 \
        acc[ta][tr] = __builtin_amdgcn_mfma_f32_16x16x32_bf16(afr, bfr[tr],          \
                                                              acc[ta][tr], 0, 0, 0); \
    }                                                                                \
    if (DO_PACK)                                                                     \
      *(unsigned long long*)&As[(P) ^ 1][a_off] = pack4bf(AV);                       \
    if (DO_A) {                                                                      \
      const float* sA = srcA + (size_t)((KK) + 3) * BK * P_;                         \
      _Pragma("unroll")                                                              \
      for (int j = 0; j < 4; ++j) AV[j] = sA[j * P_];                                \
      FENCE();                                                                       \
    }                                                                                \
    BAR_VM(VMN);                                                                     \
  }

__global__ __launch_bounds__(512, 4) void k_gemm_att(const float* __restrict__ enc,
                                                     const u16* __restrict__ Wt,
                                                     const float* __restrict__ dec_att,
                                                     const float* __restrict__ benc,
                                                     const float* __restrict__ wfull,
                                                     const float* __restrict__ bfull,
                                                     float* __restrict__ att) {
    __shared__ u16   As[2][4 * 512];     // 4 KB/buf: 64 rows x 32 k, frag order
    __shared__ u16   Bs[2][32 * 512];    // 32 KB/buf: 512 a-rows x 32 k, frag order
    __shared__ float decL[2][512];
    __shared__ float wL[512];
    float* att_part = (float*)&As[0][0]; // aliased: As[0] dead before epilogue use

    const int t    = threadIdx.x;
    const int lane = t & 63;
    const int wv   = t >> 6;             // 0..7 : wave = 64-wide a-slice
    const int l16  = lane & 15;
    const int lq   = lane >> 4;
    const int row0 = blockIdx.x * BM;

    const int b0 = row0 / 196;
    const int b1 = (row0 + BM - 1) / 196;
    decL[0][t] = dec_att[b0 * 512 + t] + benc[t];
    decL[1][t] = dec_att[b1 * 512 + t] + benc[t];
    wL[t] = wfull[t];

    // ---- A (feats) staging map: thread = (pl, kq); 4 elems, k = kq*4+j ----
    const int kq = t & 7;                // 8 k-quads of 4
    const int pl = t >> 3;               // 0..63 local row
    const int pg = row0 + pl;
    const int bb = pg / 196;
    const int pp = pg - bb * 196;
    const float* srcA = enc + (size_t)bb * CP_ + (size_t)(kq * 4) * P_ + pp;
    // frag slot: lane16 = (pl&15) + 16*(kq>>1), u16 sub-off (kq&1)*4
    const int a_off = (pl >> 4) * 512 + ((pl & 15) + 16 * (kq >> 1)) * 8 + (kq & 1) * 4;

    // ---- B (Wt) DMA: wave wv stages frag-rows wv*4..wv*4+3 (a = wv*64..+63)
    const u16* srcB  = Wt + (size_t)(wv * 64 + l16) * C_ + lq * 8;
    const int  b_off = (wv * 4) * 512 + lane * 8;

    f32x4 acc[4][4] = {};                // [ta][tr]

    // ---- prologue ---------------------------------------------------------
    float avT[4], av0[4], av1[4];
#pragma unroll
    for (int j = 0; j < 4; ++j) avT[j] = srcA[(size_t)j * P_];          // k=0
    gl_lds16(srcB,                   &Bs[0][b_off]);                    // B(0)
    gl_lds16(srcB + (size_t)16 * C_, &Bs[0][b_off + 512]);
    gl_lds16(srcB + (size_t)32 * C_, &Bs[0][b_off + 1024]);
    gl_lds16(srcB + (size_t)48 * C_, &Bs[0][b_off + 1536]);
    FENCE();
#pragma unroll
    for (int j = 0; j < 4; ++j) av1[j] = srcA[(size_t)1 * BK * P_ + j * P_];  // k=1
#pragma unroll
    for (int j = 0; j < 4; ++j) av0[j] = srcA[(size_t)2 * BK * P_ + j * P_];  // k=2
    FENCE();
    *(unsigned long long*)&As[0][a_off] = pack4bf(avT);   // waits avT only
    BAR_VM(8);                           // drain B(0); leave av1,av0 in flight

    // ---- main loop: bodies 0..59 full, tails peeled ----------------------
#pragma unroll 1
    for (int k = 0; k < 60; k += 2) {
        GEMM_BODY(k,     0, av1, 1, 1, 1, 4);
        GEMM_BODY(k + 1, 1, av0, 1, 1, 1, 4);
    }
    GEMM_BODY(60, 0, av1, 1, 1, 1, 4);   // packs k=61, loads A(63) into av1
    GEMM_BODY(61, 1, av0, 1, 1, 0, 0);   // packs k=62; conservative drain
    GEMM_BODY(62, 0, av1, 1, 1, 0, 0);   // packs k=63; conservative drain
    GEMM_BODY(63, 1, av0, 0, 0, 0, 0);   // compute only

    // ---- epilogue: relu + dot(w_full), reduce over a ---------------------
    const int col = l16, quad = lq;
#pragma unroll
    for (int tr = 0; tr < 4; ++tr) {
        int rgl = tr * 16 + col;
        int bi  = (row0 + rgl) / 196 - b0;
        float s = 0.0f;
#pragma unroll
        for (int ta = 0; ta < 4; ++ta)
#pragma unroll
            for (int rr = 0; rr < 4; ++rr) {
                int a_idx = wv * 64 + ta * 16 + quad * 4 + rr;
                float v = acc[ta][tr][rr] + decL[bi][a_idx];
                s = fmaf(fmaxf(v, 0.0f), wL[a_idx], s);
            }
        s += __shfl_xor(s, 16);
        s += __shfl_xor(s, 32);
        if (quad == 0) att_part[wv * 64 + rgl] = s;
    }
    __syncthreads();
    if (t < BM) {
        float s = bfull[0];
#pragma unroll
        for (int w = 0; w < 8; ++w) s += att_part[w * 64 + t];
        att[row0 + t] = s;
    }
}

// ---------------------------------------------------------------------------
// Kernel 4: softmax over 196 pixels per batch (1 wave per batch)
// ---------------------------------------------------------------------------
__global__ __launch_bounds__(64) void k_softmax(const float* __restrict__ att,
                                                float* __restrict__ alpha) {
    int b = blockIdx.x, lane = threadIdx.x;
    const float* a = att + b * P_;
    float v[4];
    float mx = -__builtin_inff();
#pragma unroll
    for (int i = 0; i < 4; ++i) {
        int p = lane + i * 64;
        v[i] = (p < P_) ? a[p] : -__builtin_inff();
        mx = fmaxf(mx, v[i]);
    }
#pragma unroll
    for (int off = 32; off >= 1; off >>= 1) mx = fmaxf(mx, __shfl_xor(mx, off));
    float sum = 0.0f;
#pragma unroll
    for (int i = 0; i < 4; ++i) {
        int p = lane + i * 64;
        float e = (p < P_) ? expf(v[i] - mx) : 0.0f;
        v[i] = e;
        sum += e;
    }
#pragma unroll
    for (int off = 32; off >= 1; off >>= 1) sum += __shfl_xor(sum, off);
    float inv = 1.0f / sum;
#pragma unroll
    for (int i = 0; i < 4; ++i) {
        int p = lane + i * 64;
        if (p < P_) alpha[b * P_ + p] = v[i] * inv;
    }
}

// ---------------------------------------------------------------------------
// Kernel 5: context[b][c] = sum_p enc[b][c][p] * alpha[b][p]   (fp32 exact)
// block = (b, 64-c chunk), 4 waves; wave: 4 rows/pass via 16-lane groups,
// alpha hoisted to registers once, 4-shuffle reduce.
// ---------------------------------------------------------------------------
__global__ __launch_bounds__(256) void k_context(const float* __restrict__ enc,
                                                 const float* __restrict__ alpha,
                                                 float* __restrict__ ctx) {
    __shared__ float aL[200];
    int t = threadIdx.x;
    int b = blockIdx.x >> 5;
    int chunk = blockIdx.x & 31;
    if (t < P_) aL[t] = alpha[b * P_ + t];
    __syncthreads();
    int wv = t >> 6, l = t & 63, g = l >> 4, j = l & 15;
    float4 a0 = *(const float4*)&aL[j * 4];         // p =   0..63  (lane-fixed)
    float4 a1 = *(const float4*)&aL[64 + j * 4];    // p =  64..127
    float4 a2 = *(const float4*)&aL[128 + j * 4];   // p = 128..191
    float4 a3 = *(const float4*)&aL[192];           // p = 192..195 (uniform)
    const float* base = enc + (size_t)b * CP_ + (size_t)(chunk * 64) * P_;
#pragma unroll
    for (int pass = 0; pass < 4; ++pass) {
        int r = wv * 16 + pass * 4 + g;             // 0..63, bijective
        const float* row = base + (size_t)r * P_;
        float4 f0 = *(const float4*)(row + j * 4);
        float4 f1 = *(const float4*)(row + 64 + j * 4);
        float4 f2 = *(const float4*)(row + 128 + j * 4);
        float s = f0.x * a0.x + f0.y * a0.y + f0.z * a0.z + f0.w * a0.w;
        s += f1.x * a1.x + f1.y * a1.y + f1.z * a1.z + f1.w * a1.w;
        s += f2.x * a2.x + f2.y * a2.y + f2.z * a2.z + f2.w * a2.w;
        if (j == 0) {
            float4 f3 = *(const float4*)(row + 192);
            s += f3.x * a3.x + f3.y * a3.y + f3.z * a3.z + f3.w * a3.w;
        }
        s += __shfl_xor(s, 1);
        s += __shfl_xor(s, 2);
        s += __shfl_xor(s, 4);
        s += __shfl_xor(s, 8);
        if (j == 0) ctx[(size_t)b * C_ + chunk * 64 + r] = s;
    }
}

// ---------------------------------------------------------------------------
extern "C" void kernel_launch(void* const* d_in, const int* in_sizes, int n_in,
                              void* d_out, int out_size, void* d_ws, size_t ws_size,
                              hipStream_t stream) {
    const float* enc   = (const float*)d_in[0];
    const float* dh    = (const float*)d_in[1];
    const float* Wenc  = (const float*)d_in[2];
    const float* benc  = (const float*)d_in[3];
    const float* Wdec  = (const float*)d_in[4];
    const float* bdec  = (const float*)d_in[5];
    const float* wfull = (const float*)d_in[6];
    const float* bfull = (const float*)d_in[7];

    u16*   Wt  = (u16*)d_ws;                                        // 2 MB
    float* dec = (float*)((char*)d_ws + (2u << 20));                // 512 KB
    float* att = (float*)((char*)d_ws + (2u << 20) + (512u << 10)); // 200 KB

    float* ctx     = (float*)d_out;          // [256][2048]
    float* alpha_o = ctx + B_ * C_;          // [256][196]

    k_transpose_wenc<<<dim3(256), dim3(256), 0, stream>>>(Wenc, Wt);
    k_dec_att<<<dim3(256), dim3(512), 0, stream>>>(dh, Wdec, bdec, dec);
    k_gemm_att<<<dim3(NBLK), dim3(512), 0, stream>>>(enc, Wt, dec, benc,
                                                     wfull, bfull, att);
    k_softmax<<<dim3(256), dim3(64), 0, stream>>>(att, alpha_o);
    k_context<<<dim3(256 * 32), dim3(256), 0, stream>>>(enc, alpha_o, ctx);
}

// Round 4
// 861.114 us; speedup vs baseline: 1.0687x; 1.0687x over previous
//
#include <hip/hip_runtime.h>

typedef unsigned short u16;
typedef __bf16 bf16x8 __attribute__((ext_vector_type(8)));
typedef float f32x4 __attribute__((ext_vector_type(4)));

#define B_   256
#define C_   2048
#define P_   196
#define A_   512
#define CP_  (C_ * P_)        // 401408
#define MTOT (B_ * P_)        // 50176 = 392 * 128

#define BM 128                // rows per block
#define BK 32                 // k per iter (one 16x16x32 kstep)
#define NBLK (MTOT / BM)      // 392

__device__ __forceinline__ u16 f2bf(float f) {
    unsigned int x = __float_as_uint(f);
    unsigned int r = (x + 0x7fffu + ((x >> 16) & 1u)) >> 16;   // RNE
    return (u16)r;
}

__device__ __forceinline__ unsigned long long pack4bf(const float* v) {
    unsigned int lo = (unsigned int)f2bf(v[0]) | ((unsigned int)f2bf(v[1]) << 16);
    unsigned int hi = (unsigned int)f2bf(v[2]) | ((unsigned int)f2bf(v[3]) << 16);
    return (unsigned long long)lo | ((unsigned long long)hi << 32);
}

// async global->LDS 16B copy; LDS dest is wave-uniform base + lane*16
__device__ __forceinline__ void gl_lds16(const void* g, void* l) {
    __builtin_amdgcn_global_load_lds(
        (const __attribute__((address_space(1))) unsigned int*)g,
        (__attribute__((address_space(3))) unsigned int*)l, 16, 0, 0);
}

// Compiler-level fence: pins program (and thus vmcnt-FIFO) order of memory ops.
#define FENCE() asm volatile("" ::: "memory")

// ---------------------------------------------------------------------------
// Kernel 1: Wt[a][c] = bf16(W_enc[c][a])   (2048x512 -> 512x2048)
// ---------------------------------------------------------------------------
__global__ __launch_bounds__(256) void k_transpose_wenc(const float* __restrict__ W,
                                                        u16* __restrict__ Wt) {
    __shared__ u16 tile[64][65];
    int t  = threadIdx.x;
    int cb = (blockIdx.x & 31) * 64;
    int ab = (blockIdx.x >> 5) * 64;
#pragma unroll
    for (int i = 0; i < 16; ++i) {
        int c = (t >> 6) + i * 4;
        int a = t & 63;
        tile[c][a] = f2bf(W[(size_t)(cb + c) * A_ + ab + a]);
    }
    __syncthreads();
#pragma unroll
    for (int i = 0; i < 16; ++i) {
        int a  = (t >> 6) + i * 4;
        int cl = t & 63;
        Wt[(size_t)(ab + a) * C_ + cb + cl] = tile[cl][a];
    }
}

// ---------------------------------------------------------------------------
// Kernel 2: dec_att[b][a] = dh[b] @ W_dec[:,a] + b_dec[a]
// ---------------------------------------------------------------------------
__global__ __launch_bounds__(512) void k_dec_att(const float* __restrict__ dh,
                                                 const float* __restrict__ Wd,
                                                 const float* __restrict__ bd,
                                                 float* __restrict__ out) {
    __shared__ float hL[512];
    int b = blockIdx.x, t = threadIdx.x;
    hL[t] = dh[b * 512 + t];
    __syncthreads();
    float s = bd[t];
#pragma unroll 8
    for (int k = 0; k < 512; ++k) s = fmaf(hL[k], Wd[k * 512 + t], s);
    out[b * 512 + t] = s;
}

// ---------------------------------------------------------------------------
// Kernel 3: fused att GEMM.  Round-0 geometry (BM=128, 1024 thr = 16 waves,
// wave tile 64r x 64a, 392 blocks) + counted-vmcnt pipeline:
//
//   body k (single barrier, all buffers double-buffered):
//     1. pack AV(k+1) -> As[p^1]     <- FIRST: the only outstanding VM ops
//        here are the 4 A-gathers from last body (issued a full body ago),
//        so the compiler's conservative wait is nearly free.
//     2. issue B(k+1) DMA (2x global_load_lds dwordx4) -> Bs[p^1]
//     3. issue A(k+2) gather (4 fp32) -> AVN            [stays in regs]
//     4. ds_read frags from As[p]/Bs[p]; 16 x MFMA (setprio-wrapped)
//     5. asm s_waitcnt vmcnt(4) lgkmcnt(0); sched_barrier; s_barrier
//        -> FIFO retires exactly the 2 B-DMA ops; the 4 A-gathers stay in
//           flight ACROSS the barrier (T4, counted-vmcnt).
//   B-DMA latency is covered by ds_read+MFMA; A-gather gets a full body.
//   No __syncthreads() in the loop => no vmcnt(0) drain anywhere.
// ---------------------------------------------------------------------------
#define GBODY(KK, P, AVP, AVN, DO_PACK, DO_B, DO_A, VMN)                             \
  {                                                                                  \
    if (DO_PACK)                                                                     \
      *(unsigned long long*)&As[(P) ^ 1][a_off] = pack4bf(AVP);                      \
    if (DO_B) {                                                                      \
      const u16* sB = srcB + (size_t)((KK) + 1) * 32;                                \
      gl_lds16(sB,                   &Bs[(P) ^ 1][b_off]);                           \
      gl_lds16(sB + (size_t)16 * C_, &Bs[(P) ^ 1][b_off + 512]);                     \
      FENCE();                                                                       \
    }                                                                                \
    if (DO_A) {                                                                      \
      const float* sA = srcA + (size_t)((KK) + 2) * BK * P_;                         \
      _Pragma("unroll")                                                              \
      for (int j = 0; j < 4; ++j) AVN[j] = sA[(size_t)j * P_];                       \
      FENCE();                                                                       \
    }                                                                                \
    bf16x8 bfr[4], afr[4];                                                           \
    _Pragma("unroll")                                                                \
    for (int tr = 0; tr < 4; ++tr)                                                   \
      bfr[tr] = *(const bf16x8*)&As[P][(wr * 4 + tr) * 512 + lane * 8];              \
    _Pragma("unroll")                                                                \
    for (int ta = 0; ta < 4; ++ta)                                                   \
      afr[ta] = *(const bf16x8*)&Bs[P][(wa * 4 + ta) * 512 + lane * 8];              \
    __builtin_amdgcn_s_setprio(1);                                                   \
    _Pragma("unroll")                                                                \
    for (int ta = 0; ta < 4; ++ta)                                                   \
      _Pragma("unroll")                                                              \
      for (int tr = 0; tr < 4; ++tr)                                                 \
        acc[ta][tr] = __builtin_amdgcn_mfma_f32_16x16x32_bf16(afr[ta], bfr[tr],      \
                                                              acc[ta][tr], 0, 0, 0); \
    __builtin_amdgcn_s_setprio(0);                                                   \
    asm volatile("s_waitcnt vmcnt(" #VMN ") lgkmcnt(0)" ::: "memory");               \
    __builtin_amdgcn_sched_barrier(0);                                               \
    __builtin_amdgcn_s_barrier();                                                    \
  }

__global__ __launch_bounds__(1024, 4) void k_gemm_att(const float* __restrict__ enc,
                                                      const u16* __restrict__ Wt,
                                                      const float* __restrict__ dec_att,
                                                      const float* __restrict__ benc,
                                                      const float* __restrict__ wfull,
                                                      const float* __restrict__ bfull,
                                                      float* __restrict__ att) {
    __shared__ u16   As[2][8 * 512];     // 8 KB/buf : feats frags, 8 rgrps
    __shared__ u16   Bs[2][32 * 512];    // 32 KB/buf: Wt frags, 32 agrps
    __shared__ float decL[2][512];
    __shared__ float wL[512];
    float* att_part = (float*)&As[0][0]; // 4 KB alias; As[0] dead at epilogue

    const int t    = threadIdx.x;
    const int lane = t & 63;
    const int wv   = t >> 6;             // 0..15
    const int l16  = lane & 15;
    const int lq   = lane >> 4;
    const int row0 = blockIdx.x * BM;

    const int b0 = row0 / 196;
    const int b1 = (row0 + BM - 1) / 196;
    if (t < 512) {
        decL[0][t] = dec_att[b0 * 512 + t] + benc[t];
        wL[t] = wfull[t];
    } else {
        decL[1][t - 512] = dec_att[b1 * 512 + (t - 512)] + benc[t - 512];
    }

    // ---- A (feats) staging map: thread = (pl, kq); 4 elems, k = kq*4+j ----
    const int kq = t & 7;                // 8 k-quads of 4
    const int pl = t >> 3;               // 0..127 local row
    const int pg = row0 + pl;
    const int bb = pg / 196;
    const int pp = pg - bb * 196;
    const float* srcA = enc + (size_t)bb * CP_ + (size_t)(kq * 4) * P_ + pp;
    // frag slot: lane16 = (pl&15) + 16*(kq>>1), u16 sub-off (kq&1)*4
    const int a_off = (pl >> 4) * 512 + ((pl & 15) + 16 * (kq >> 1)) * 8 + (kq & 1) * 4;

    // ---- B (Wt) DMA: wave wv stages agrps 2wv, 2wv+1 ----------------------
    const u16* srcB  = Wt + (size_t)(wv * 2 * 16 + l16) * C_ + lq * 8;
    const int  b_off = (wv * 2) * 512 + lane * 8;

    // ---- wave tile --------------------------------------------------------
    const int wr = wv & 1;               // 64-row half
    const int wa = wv >> 1;              // 0..7 : 64-a slice

    f32x4 acc[4][4] = {};                // [ta][tr]
    float av0[4], av1[4];

    // ---- prologue: A(0)->As[0], B(0)->Bs[0], A(1)->av0 -------------------
#pragma unroll
    for (int j = 0; j < 4; ++j) av0[j] = srcA[(size_t)j * P_];            // A(0)
    *(unsigned long long*)&As[0][a_off] = pack4bf(av0);                   // waits A(0) only
    gl_lds16(srcB,                   &Bs[0][b_off]);                      // B(0)
    gl_lds16(srcB + (size_t)16 * C_, &Bs[0][b_off + 512]);
    FENCE();
#pragma unroll
    for (int j = 0; j < 4; ++j) av0[j] = srcA[(size_t)BK * P_ + (size_t)j * P_];  // A(1)
    FENCE();
    asm volatile("s_waitcnt vmcnt(4) lgkmcnt(0)" ::: "memory");           // drain B(0); keep A(1)
    __builtin_amdgcn_sched_barrier(0);
    __builtin_amdgcn_s_barrier();

    // ---- main loop: 64 bodies, one barrier each ---------------------------
#pragma unroll 1
    for (int k = 0; k < 62; k += 2) {
        GBODY(k,     0, av0, av1, 1, 1, 1, 4);
        GBODY(k + 1, 1, av1, av0, 1, 1, 1, 4);
    }
    GBODY(62, 0, av0, av1, 1, 1, 0, 0);  // packs A(63), DMA B(63); full drain
    GBODY(63, 1, av1, av0, 0, 0, 0, 0);  // compute only

    // ---- epilogue: relu + dot(w_full), reduce over a ---------------------
    const int col = l16, quad = lq;
#pragma unroll
    for (int tr = 0; tr < 4; ++tr) {
        int rgl = wr * 64 + tr * 16 + col;
        int bi  = (row0 + rgl) / 196 - b0;
        float s = 0.0f;
#pragma unroll
        for (int ta = 0; ta < 4; ++ta)
#pragma unroll
            for (int rr = 0; rr < 4; ++rr) {
                int a_idx = wa * 64 + ta * 16 + quad * 4 + rr;
                float v = acc[ta][tr][rr] + decL[bi][a_idx];
                s = fmaf(fmaxf(v, 0.0f), wL[a_idx], s);
            }
        s += __shfl_xor(s, 16);
        s += __shfl_xor(s, 32);
        if (quad == 0) att_part[wa * 128 + rgl] = s;
    }
    __syncthreads();
    if (t < BM) {
        float s = bfull[0];
#pragma unroll
        for (int w = 0; w < 8; ++w) s += att_part[w * 128 + t];
        att[row0 + t] = s;
    }
}

// ---------------------------------------------------------------------------
// Kernel 4: softmax over 196 pixels per batch (1 wave per batch)
// ---------------------------------------------------------------------------
__global__ __launch_bounds__(64) void k_softmax(const float* __restrict__ att,
                                                float* __restrict__ alpha) {
    int b = blockIdx.x, lane = threadIdx.x;
    const float* a = att + b * P_;
    float v[4];
    float mx = -__builtin_inff();
#pragma unroll
    for (int i = 0; i < 4; ++i) {
        int p = lane + i * 64;
        v[i] = (p < P_) ? a[p] : -__builtin_inff();
        mx = fmaxf(mx, v[i]);
    }
#pragma unroll
    for (int off = 32; off >= 1; off >>= 1) mx = fmaxf(mx, __shfl_xor(mx, off));
    float sum = 0.0f;
#pragma unroll
    for (int i = 0; i < 4; ++i) {
        int p = lane + i * 64;
        float e = (p < P_) ? expf(v[i] - mx) : 0.0f;
        v[i] = e;
        sum += e;
    }
#pragma unroll
    for (int off = 32; off >= 1; off >>= 1) sum += __shfl_xor(sum, off);
    float inv = 1.0f / sum;
#pragma unroll
    for (int i = 0; i < 4; ++i) {
        int p = lane + i * 64;
        if (p < P_) alpha[b * P_ + p] = v[i] * inv;
    }
}

// ---------------------------------------------------------------------------
// Kernel 5: context[b][c] = sum_p enc[b][c][p] * alpha[b][p]   (fp32 exact)
// (unchanged for clean attribution; will surface in top-5 once gemm drops)
// ---------------------------------------------------------------------------
__global__ __launch_bounds__(256) void k_context(const float* __restrict__ enc,
                                                 const float* __restrict__ alpha,
                                                 float* __restrict__ ctx) {
    __shared__ float aL[200];
    int t = threadIdx.x;
    int b = blockIdx.x >> 5;
    int chunk = blockIdx.x & 31;
    if (t < P_) aL[t] = alpha[b * P_ + t];
    __syncthreads();
    int wv = t >> 6, l = t & 63, g = l >> 4, j = l & 15;
    float4 a0 = *(const float4*)&aL[j * 4];         // p =   0..63  (lane-fixed)
    float4 a1 = *(const float4*)&aL[64 + j * 4];    // p =  64..127
    float4 a2 = *(const float4*)&aL[128 + j * 4];   // p = 128..191
    float4 a3 = *(const float4*)&aL[192];           // p = 192..195 (uniform)
    const float* base = enc + (size_t)b * CP_ + (size_t)(chunk * 64) * P_;
#pragma unroll
    for (int pass = 0; pass < 4; ++pass) {
        int r = wv * 16 + pass * 4 + g;             // 0..63, bijective
        const float* row = base + (size_t)r * P_;
        float4 f0 = *(const float4*)(row + j * 4);
        float4 f1 = *(const float4*)(row + 64 + j * 4);
        float4 f2 = *(const float4*)(row + 128 + j * 4);
        float s = f0.x * a0.x + f0.y * a0.y + f0.z * a0.z + f0.w * a0.w;
        s += f1.x * a1.x + f1.y * a1.y + f1.z * a1.z + f1.w * a1.w;
        s += f2.x * a2.x + f2.y * a2.y + f2.z * a2.z + f2.w * a2.w;
        if (j == 0) {
            float4 f3 = *(const float4*)(row + 192);
            s += f3.x * a3.x + f3.y * a3.y + f3.z * a3.z + f3.w * a3.w;
        }
        s += __shfl_xor(s, 1);
        s += __shfl_xor(s, 2);
        s += __shfl_xor(s, 4);
        s += __shfl_xor(s, 8);
        if (j == 0) ctx[(size_t)b * C_ + chunk * 64 + r] = s;
    }
}

// ---------------------------------------------------------------------------
extern "C" void kernel_launch(void* const* d_in, const int* in_sizes, int n_in,
                              void* d_out, int out_size, void* d_ws, size_t ws_size,
                              hipStream_t stream) {
    const float* enc   = (const float*)d_in[0];
    const float* dh    = (const float*)d_in[1];
    const float* Wenc  = (const float*)d_in[2];
    const float* benc  = (const float*)d_in[3];
    const float* Wdec  = (const float*)d_in[4];
    const float* bdec  = (const float*)d_in[5];
    const float* wfull = (const float*)d_in[6];
    const float* bfull = (const float*)d_in[7];

    u16*   Wt  = (u16*)d_ws;                                        // 2 MB
    float* dec = (float*)((char*)d_ws + (2u << 20));                // 512 KB
    float* att = (float*)((char*)d_ws + (2u << 20) + (512u << 10)); // 200 KB

    float* ctx     = (float*)d_out;          // [256][2048]
    float* alpha_o = ctx + B_ * C_;          // [256][196]

    k_transpose_wenc<<<dim3(256), dim3(256), 0, stream>>>(Wenc, Wt);
    k_dec_att<<<dim3(256), dim3(512), 0, stream>>>(dh, Wdec, bdec, dec);
    k_gemm_att<<<dim3(NBLK), dim3(1024), 0, stream>>>(enc, Wt, dec, benc,
                                                      wfull, bfull, att);
    k_softmax<<<dim3(256), dim3(64), 0, stream>>>(att, alpha_o);
    k_context<<<dim3(256 * 32), dim3(256), 0, stream>>>(enc, alpha_o, ctx);
}